// Round 6
// baseline (753.222 us; speedup 1.0000x reference)
//
#include <hip/hip_runtime.h>
#include <hip/hip_bf16.h>

// Net_22625887715641: fused conv-feats + channel-normalize + 32x32 normalized
// cross-correlation (23x23 shifts, 362x362 templates).
//
// R16 vs R15 (corr 149us, MfmaUtil 47%):
//  R15 post-mortem: wall 15.6k cyc/CU/y = MFMA 6.9k/SIMD + LDS ~9.2k
//  (1152 ds_read_b64/y at ~8cyc instruction cost) with poor overlap
//  (lockstep 650-cyc Kt rounds). Both pipes must shrink:
//  - MX-scaled MFMA: mfma_scale_f32_32x32x64_f8f6f4 with unit scales
//    (E8M0 0x7F = 1.0). K/instr 16->64: 18 MFMA/wave/y (was 72) at
//    2.15x the FLOP rate (4686 vs 2190 TF ubench) -> MFMA pipe 3.7k.
//    Same fp8 e4m3 inputs; scales=1 -> numerics as before.
//  - Operands read 32B/lane in wide ops: A = 2x ds_read_b128 (16B-
//    aligned, bank-uniform via new filtb layout), B = 4x ds_read_b64
//    (8B-aligned in the shifted-copy scheme; compiler merges to
//    ds_read2_b64). 8 LDS instr/wave/kt64 vs 16 -> LDS ~6.9k cyc/y.
//  - filtb repacked [row][kt64 6][h 2][kg 2][o 32][16B] (pack_kernel
//    indexing change only; A-ring copies rows verbatim, layout-agnostic).
//  - A-ring / B staging / barriers / epilogue unchanged (C/D layout is
//    shape-determined, same for scaled 32x32).
//  - feat/prep unchanged.

typedef unsigned short ushort_t;
typedef unsigned int uint_t;
typedef unsigned char uchar_t;
typedef __attribute__((ext_vector_type(4))) float f32x4;
typedef __attribute__((ext_vector_type(16))) float f32x16;
typedef __attribute__((ext_vector_type(4))) uint_t uint4_t;
typedef __attribute__((ext_vector_type(2))) uint_t uint2_t;
typedef __attribute__((ext_vector_type(8))) int int8v;

#define EPSF 2.2204460492503131e-16f
#define X1_N (32*384*384)
#define X2_N (32*32*23*23)

// filtb: fp8 [372 rows][kt64 6][h 2][kg 2][o 32][16B]; row = yf+5
#define FILTB_ROW_B 12288
#define FILTB_BYTES (372*48*32*8)
// prevb: fp8 [32 c][385 rows][432 x]; data rows 0..383 cols 0..383; zeros else
#define PREVB_STRIDE 432
#define PREVB_BYTES (32*385*PREVB_STRIDE)
#define ZERO_BYTES ((size_t)FILTB_BYTES + PREVB_BYTES)
// fT2: fp32 [16 chp][45 rows][12] after prevb
#define FT2_ELEMS (16*45*12)

#define YMAX 367            // y-steps 0..366
#define NCHUNKS 16          // 16 chpairs x 16 chunks = 256 blocks = 1/CU
#define INV_AREA (1.0f/131044.0f)

// One prev y-row image in LDS: [dyb 4][copy 8][432]; copy stride 432
#define SB_COPY_B 432
#define SB_DYB_B  (8*SB_COPY_B)     // 3456
#define SB_ROW_B  (4*SB_DYB_B)      // 13824 B per y-row image
#define SB_BYTES  (2*2*SB_ROW_B)    // [group][buf] = 55296 B

// A-ring: 8 slots x one filtb row
#define SA_BYTES  (8*FILTB_ROW_B)   // 98304 B
#define SMEM_TOTAL (SA_BYTES + SB_BYTES)   // 153600 B

// ---------------------------------------------------------------------------
// fp32 -> fp8 e4m3 (OCP), RNE, input assumed in [0, 448).
// ---------------------------------------------------------------------------
__device__ __forceinline__ uint_t f32_to_e4m3(float f) {
  if (f < 0.015625f)                         // subnormal: m * 2^-9
    return (uint_t)__float2int_rn(f * 512.0f);
  uint_t b = __builtin_bit_cast(uint_t, f);
  int e = (int)(b >> 23) - 127;
  uint_t m = b & 0x7FFFFFu;
  uint_t keep = m >> 20;
  uint_t rest = m & 0xFFFFFu;
  keep += (rest > 0x80000u) || (rest == 0x80000u && (keep & 1u));
  if (keep == 8u) { keep = 0u; e += 1; }
  if (e > 8) return 0x7Eu;                   // saturate 448
  return (uint_t)(((e + 7) << 3) | keep);
}

// ---------------------------------------------------------------------------
// Prep: pack filters to [chp][45][12] (rows 16B-aligned, b-contiguous).
// ---------------------------------------------------------------------------
__global__ void prep_kernel(const float* __restrict__ ft, const float* __restrict__ fn,
                            float* __restrict__ fT2)
{
  const int e = blockIdx.x * 256 + threadIdx.x;
  if (e < FT2_ELEMS) {
    const int chp = e / 540;
    const int rem = e - chp * 540;
    const int row = rem / 12;
    const int j = rem - row * 12;
    float v = 0.f;
    if (j < 11) {
      if (row < 33)      v = ft[chp * 363 + row * 11 + j];        // row = t*11+a
      else if (row < 44) v = fn[chp * 121 + (row - 33) * 11 + j]; // row-33 = a
    }
    fT2[e] = v;
  }
}

// ---------------------------------------------------------------------------
// Stage 1: thread = (ch-pair chp) x (16-px row). Block 128 = 8 rows x 16 chp.
// mode 0: x -> x1 (fp32). mode 1: xprev -> prevb (fp8 e4m3).
// ---------------------------------------------------------------------------
__global__ __launch_bounds__(128, 4) void feat_kernel(
    const float* __restrict__ xcur, const float* __restrict__ xprev,
    const float* __restrict__ fT2,
    float* __restrict__ out_x1, uchar_t* __restrict__ prevb)
{
  __shared__ float sPx[3 * 18 * 28];
  const int tid = threadIdx.x;
  const int chp = tid & 15;
  const int r = tid >> 4;              // 0..7
  const int j0 = blockIdx.x * 16;
  const int i0 = blockIdx.y * 8;
  const int i = i0 + r;
  const int mode = blockIdx.z;
  const float* __restrict__ xin = mode ? xprev : xcur;

  for (int e = tid; e < 3 * 18 * 26; e += 128) {
    const int t = e / 468;
    const int rem = e - t * 468;
    const int ri = rem / 26;
    const int ci = rem - ri * 26;
    sPx[(t * 18 + ri) * 28 + ci] = xin[((size_t)t * 394 + i0 + ri) * 394 + j0 + ci];
  }
  __syncthreads();

  const float* __restrict__ fbase = fT2 + chp * 540;

  float accT[16], accN[16];
#pragma unroll
  for (int p = 0; p < 16; ++p) { accT[p] = 0.f; accN[p] = 0.f; }

#pragma unroll
  for (int t = 0; t < 3; ++t) {
    for (int a = 0; a < 11; ++a) {
      const float* row = &sPx[(t * 18 + r + a) * 28];
      float wv[26];
#pragma unroll
      for (int k = 0; k < 6; ++k) {
        const f32x4 q = *(const f32x4*)(row + 4 * k);
        wv[4 * k + 0] = q[0]; wv[4 * k + 1] = q[1];
        wv[4 * k + 2] = q[2]; wv[4 * k + 3] = q[3];
      }
      wv[24] = row[24]; wv[25] = row[25];

      const float* fr = fbase + (t * 11 + a) * 12;
      const f32x4 fq0 = *(const f32x4*)(fr);
      const f32x4 fq1 = *(const f32x4*)(fr + 4);
      const f32x4 fq2 = *(const f32x4*)(fr + 8);
      float fv[12];
#pragma unroll
      for (int k = 0; k < 4; ++k) { fv[k] = fq0[k]; fv[4+k] = fq1[k]; fv[8+k] = fq2[k]; }
      float fv2[12];
      if (t == 2) {
        const float* fr2 = fbase + (33 + a) * 12;
        const f32x4 g0 = *(const f32x4*)(fr2);
        const f32x4 g1 = *(const f32x4*)(fr2 + 4);
        const f32x4 g2 = *(const f32x4*)(fr2 + 8);
#pragma unroll
        for (int k = 0; k < 4; ++k) { fv2[k] = g0[k]; fv2[4+k] = g1[k]; fv2[8+k] = g2[k]; }
      }

#pragma unroll
      for (int b = 0; b < 11; ++b) {
        const float fT = fv[b];
#pragma unroll
        for (int p = 0; p < 16; ++p) accT[p] = fmaf(wv[b + p], fT, accT[p]);
        if (t == 2) {
          const float fN = fv2[b];
#pragma unroll
          for (int p = 0; p < 16; ++p) accN[p] = fmaf(wv[b + p], fN, accN[p]);
        }
      }
    }
  }

  float o0[16], o1[16];
#pragma unroll
  for (int p = 0; p < 16; ++p) {
    const float vT = fmaxf(accT[p], 0.f) * 0.5f;   // temp: relu(conv)/2
    const float vN = fmaxf(accN[p], 0.f);
    float s = vT + vN;
    s += __shfl_xor(s, 1);  s += __shfl_xor(s, 2);
    s += __shfl_xor(s, 4);  s += __shfl_xor(s, 8);
    const float inv = 1.f / (s + EPSF);
    o0[p] = vT * inv;
    o1[p] = vN * inv;
  }

  if (mode == 0) {
#pragma unroll
    for (int q = 0; q < 4; ++q) {
      f32x4 v0 = {o0[4*q], o0[4*q+1], o0[4*q+2], o0[4*q+3]};
      f32x4 v1 = {o1[4*q], o1[4*q+1], o1[4*q+2], o1[4*q+3]};
      *(f32x4*)(out_x1 + (size_t)chp * 147456 + i * 384 + j0 + 4 * q) = v0;
      *(f32x4*)(out_x1 + (size_t)(chp + 16) * 147456 + i * 384 + j0 + 4 * q) = v1;
    }
  } else {
    uint4_t u0, u1;
#pragma unroll
    for (int q = 0; q < 4; ++q) {
      u0[q] = f32_to_e4m3(o0[4*q]) | (f32_to_e4m3(o0[4*q+1]) << 8) |
              (f32_to_e4m3(o0[4*q+2]) << 16) | (f32_to_e4m3(o0[4*q+3]) << 24);
      u1[q] = f32_to_e4m3(o1[4*q]) | (f32_to_e4m3(o1[4*q+1]) << 8) |
              (f32_to_e4m3(o1[4*q+2]) << 16) | (f32_to_e4m3(o1[4*q+3]) << 24);
    }
    *(uint4_t*)(prevb + ((size_t)chp * 385 + i) * PREVB_STRIDE + j0) = u0;
    *(uint4_t*)(prevb + ((size_t)(chp + 16) * 385 + i) * PREVB_STRIDE + j0) = u1;
  }
}

// ---------------------------------------------------------------------------
// Pack x1 (fp32, cropped) into filtb fp8 MFMA-A layout; coalesced 8B writes.
// New layout per row: [kt64 6][h 2][kg 2][o 32][16B]; element k = xb*8+j:
// kt64 = xb>>3, kg = (xb>>2)&1, h = (xb>>1)&1, byte16 = (xb&1)*8 + j.
// ---------------------------------------------------------------------------
__global__ __launch_bounds__(256) void pack_kernel(
    const float* __restrict__ x1, uchar_t* __restrict__ filtb)
{
  const int e = blockIdx.x * 256 + threadIdx.x;
  if (e >= 362 * 46 * 32) return;
  const int o = e & 31;
  const int q = e >> 5;
  const int xb = q % 46;
  const int rowr = q / 46 + 5;          // 5..366
  const int i = rowr + 6;               // 11..372
  const int j0 = 11 + xb * 8;
  const float* src = x1 + (size_t)o * 147456 + i * 384 + j0;
  uint_t w0 = 0, w1 = 0;
#pragma unroll
  for (int k = 0; k < 4; ++k) {
    w0 |= f32_to_e4m3((j0 + k     <= 372) ? src[k]     : 0.f) << (8 * k);
    w1 |= f32_to_e4m3((j0 + 4 + k <= 372) ? src[4 + k] : 0.f) << (8 * k);
  }
  uint2_t u = {w0, w1};
  const int off = (xb >> 3) * 2048 + ((xb >> 1) & 1) * 1024 +
                  ((xb >> 2) & 1) * 512 + o * 16 + (xb & 1) * 8;
  *(uint2_t*)(filtb + (size_t)rowr * FILTB_ROW_B + off) = u;
}

// ---------------------------------------------------------------------------
// Stage 2: correlation via MX-scaled 32x32x64 fp8 MFMA (unit scales).
//   out[o,c,dy,dx] = sum_{y,x} filt[o][y-dy_a][x] * prev[c][y+6*dy_b][x+dx]
//   M=192=(dy_a 6)x(o 32); N=96: n = dyb*24+dx (dx 0..22, 23=pad);
//   K=(y, x): 6 kt64 steps of 64 per y.
// Block 768 thr = 12 waves = TWO channels (waves 0-5 ch 2p, 6-11 ch 2p+1);
// placement 3,3,3,3 -> balanced pipes. A: 8-slot LDS ring shared by both
// groups, wave w reads ring slot (y+5-w)&7. B: per-group double-buffered
// shifted-copy image (copy s = row byte-shifted by s).
// Operand map (32x32x64 f8f6f4): m/n = lane&31, k = (lane>>5)*32 + j
// (32 contiguous k bytes per lane: A 2x ds_read_b128, B 4x ds_read_b64).
// C/D map: col = lane&31, row = (reg&3)+8*(reg>>2)+4*(lane>>5).
// ---------------------------------------------------------------------------
__global__ __launch_bounds__(768, 3) void corr_kernel(
    const uchar_t* __restrict__ filtb, const uchar_t* __restrict__ prevb,
    float* __restrict__ x2)
{
  extern __shared__ uchar_t smem[];          // [A ring 98304][B 55296]

  const int tid = threadIdx.x;
  const int lane = tid & 63;
  const int wv = tid >> 6;               // 0..11
  const int cg = (wv >= 6) ? 1 : 0;      // channel sub-group
  const int w = wv - 6 * cg;             // 0..5 = dy_a
  const int kg = lane >> 5;              // k-group 0..1
  const int nn = lane & 31;              // n (or o) within tile

  const int chpair = blockIdx.x / NCHUNKS;     // 0..15
  const int chunk = blockIdx.x % NCHUNKS;      // 0..15; %8 == XCD
  const int ch = 2 * chpair + cg;              // 0..31
  const int y0 = (chunk * YMAX) / NCHUNKS;     // balanced 22-23 y-steps
  const int y1 = ((chunk + 1) * YMAX) / NCHUNKS;

  uint_t* const sBg = (uint_t*)(smem + SA_BYTES) + cg * (2 * (SB_ROW_B / 4));

  // Per-lane B window byte offsets within a y-row image (32B contiguous,
  // 8B-aligned): copy s = dx&7 is the row shifted by s bytes.
  int boffB[3];
#pragma unroll
  for (int nt = 0; nt < 3; ++nt) {
    const int n = nt * 32 + nn;          // 0..95
    const int dyb = n / 24;
    const int dxr = n - 24 * dyb;
    const int dx = (dxr < 23) ? dxr : 22;      // pad lane reads valid data
    const int s = dx & 7;
    boffB[nt] = dyb * SB_DYB_B + s * SB_COPY_B + (dx >> 3) * 8 + kg * 32;
  }

  // B staging per group: 104 tasks (dyb = t/26, 16B group g = t%26).
  const int tl = tid - cg * 384;               // 0..383 within group
  const bool st_act = (tl < 104);
  const int sdyb = st_act ? (tl / 26) : 0;
  const int sg = tl - 26 * (st_act ? (tl / 26) : 0);
  const uchar_t* srcbase = prevb + ((size_t)(ch * 385 + 6 * sdyb)) * PREVB_STRIDE;
  const int dstoff = sdyb * (SB_DYB_B / 4) + 4 * sg;   // word offset in buffer

  uint_t st0 = 0, st1 = 0, st2 = 0, st3 = 0, st4 = 0, st5 = 0;

  auto load_st = [&](int yy) {
    const uint_t* sw = (const uint_t*)(srcbase + (size_t)yy * PREVB_STRIDE) + 4 * sg;
    const uint4_t lo = *(const uint4_t*)(sw);
    const uint2_t hi = *(const uint2_t*)(sw + 4);
    st0 = lo.x; st1 = lo.y; st2 = lo.z; st3 = lo.w; st4 = hi.x; st5 = hi.y;
  };

  auto write_shift = [&](int buf) {
    uint_t* dst = sBg + buf * (SB_ROW_B / 4) + dstoff;
    const uint_t wd[6] = {st0, st1, st2, st3, st4, st5};
#pragma unroll
    for (int s = 0; s < 8; ++s) {
      const int off = s >> 2;
      const int b = (s & 3) * 8;
      uint4_t v;
      if (b == 0) {
        v = uint4_t{wd[off], wd[off + 1], wd[off + 2], wd[off + 3]};
      } else {
        v = uint4_t{(wd[off]     >> b) | (wd[off + 1] << (32 - b)),
                    (wd[off + 1] >> b) | (wd[off + 2] << (32 - b)),
                    (wd[off + 2] >> b) | (wd[off + 3] << (32 - b)),
                    (wd[off + 3] >> b) | (wd[off + 4] << (32 - b))};
      }
      *(uint4_t*)(dst + s * (SB_COPY_B / 4)) = v;
    }
  };

  // 32B operand loaders -> v8i32
  auto loadA = [](const char* aRow, int kt) -> int8v {
    const uint4_t a0 = *(const uint4_t*)(aRow + kt * 2048);          // h=0
    const uint4_t a1 = *(const uint4_t*)(aRow + kt * 2048 + 1024);   // h=1
    int8v r = {(int)a0.x, (int)a0.y, (int)a0.z, (int)a0.w,
               (int)a1.x, (int)a1.y, (int)a1.z, (int)a1.w};
    return r;
  };
  auto loadB = [](const char* p) -> int8v {
    const uint2_t b0 = *(const uint2_t*)(p);
    const uint2_t b1 = *(const uint2_t*)(p + 8);
    const uint2_t b2 = *(const uint2_t*)(p + 16);
    const uint2_t b3 = *(const uint2_t*)(p + 24);
    int8v r = {(int)b0.x, (int)b0.y, (int)b1.x, (int)b1.y,
               (int)b2.x, (int)b2.y, (int)b3.x, (int)b3.y};
    return r;
  };

  f32x16 acc[3];
#pragma unroll
  for (int nt = 0; nt < 3; ++nt)
#pragma unroll
    for (int r = 0; r < 16; ++r) acc[nt][r] = 0.f;

  // ---- Prologue ----
  // A: stage 6 filt rows y0..y0+5 into ring slots (row&7); 768 thr x 16B.
  {
    uint4_t pv[6];
#pragma unroll
    for (int r6 = 0; r6 < 6; ++r6)
      pv[r6] = *(const uint4_t*)(filtb + (size_t)(y0 + r6) * FILTB_ROW_B + tid * 16);
#pragma unroll
    for (int r6 = 0; r6 < 6; ++r6)
      *(uint4_t*)(smem + ((y0 + r6) & 7) * FILTB_ROW_B + tid * 16) = pv[r6];
  }
  // B: stage y0 into buf 0; preload y0+1 into regs.
  if (st_act) {
    load_st(y0);
    write_shift(0);
    if (y0 + 1 < y1) load_st(y0 + 1);
  }

  __syncthreads();                       // A rows y0..y0+5 + B buf0 staged

  for (int y = y0; y < y1; ++y) {
    const int pb = (y - y0) & 1;         // B buffer being read this iteration

    // A: issue global load of filt row y+6 (used from iteration y+1 on;
    // written to LDS after this K-loop -> a full K-loop of latency cover).
    const bool a_act = (y + 6 <= y1 + 4);
    uint4_t aval;
    if (a_act)
      aval = *(const uint4_t*)(filtb + (size_t)(y + 6) * FILTB_ROW_B + tid * 16);

    // B: stage y+1 into the other buffer; prefetch y+2 into regs.
    if (st_act && y + 1 < y1) write_shift(pb ^ 1);
    if (st_act && y + 2 < y1) load_st(y + 2);

    const char* sBrd = (const char*)sBg + pb * SB_ROW_B;
    const char* aRow = (const char*)smem +
        ((y + 5 - w) & 7) * FILTB_ROW_B + kg * 512 + nn * 16;

    // K-loop: 6 kt64 steps, pure LDS; A and B prefetched 1 step deep.
    int8v Af, Afn, Bf[3], Bfn[3];
    Af = loadA(aRow, 0);
#pragma unroll
    for (int nt = 0; nt < 3; ++nt)
      Bf[nt] = loadB(sBrd + boffB[nt]);

#pragma unroll
    for (int kt = 0; kt < 6; ++kt) {
      const int ktn = (kt + 1 < 6) ? kt + 1 : 5;
      Afn = loadA(aRow, ktn);
#pragma unroll
      for (int nt = 0; nt < 3; ++nt)
        Bfn[nt] = loadB(sBrd + boffB[nt] + (ktn << 6));
#pragma unroll
      for (int nt = 0; nt < 3; ++nt)
        acc[nt] = __builtin_amdgcn_mfma_scale_f32_32x32x64_f8f6f4(
            Af, Bf[nt], acc[nt], 0, 0,            // fmtA=FP8, fmtB=FP8
            0, 0x7F7F7F7F, 0, 0x7F7F7F7F);        // unit E8M0 scales
      Af = Afn;
#pragma unroll
      for (int nt = 0; nt < 3; ++nt) Bf[nt] = Bfn[nt];
    }

    // A: write staged row into ring slot (y+6)&7 — disjoint from slots
    // {y..y+5}&7 still being read by other waves; safe without a barrier.
    if (a_act)
      *(uint4_t*)(smem + ((y + 6) & 7) * FILTB_ROW_B + tid * 16) = aval;

    __syncthreads();                     // A row y+6 + B buf y+1 visible
  }

  // Epilogue: scale partials, atomically accumulate into x2[o][c][dy][dx].
#pragma unroll
  for (int nt = 0; nt < 3; ++nt) {
    const int n = nt * 32 + nn;
    const int dyb = n / 24;
    const int dxr = n - 24 * dyb;
    if (dxr < 23) {
      const int dy = w + 6 * dyb;
      if (dy <= 22) {
#pragma unroll
        for (int r = 0; r < 16; ++r) {
          const int o = (r & 3) + 8 * (r >> 2) + 4 * kg;   // C/D row
          atomicAdd(&x2[((o * 32 + ch) * 23 + dy) * 23 + dxr],
                    acc[nt][r] * INV_AREA);
        }
      }
    }
  }
}

// ---------------------------------------------------------------------------
extern "C" void kernel_launch(void* const* d_in, const int* in_sizes, int n_in,
                              void* d_out, int out_size, void* d_ws, size_t ws_size,
                              hipStream_t stream)
{
  const float* x     = (const float*)d_in[0];   // [3][394][394]
  const float* xprev = (const float*)d_in[1];
  const float* ft    = (const float*)d_in[2];   // [16][3][11][11]
  const float* fn    = (const float*)d_in[3];   // [16][1][11][11]
  float* out = (float*)d_out;

  uchar_t* filtb = (uchar_t*)d_ws;
  uchar_t* prevb = filtb + FILTB_BYTES;
  float* fT2 = (float*)(prevb + PREVB_BYTES);

  static bool attr_set = false;
  if (!attr_set) {
    (void)hipFuncSetAttribute((const void*)corr_kernel,
        hipFuncAttributeMaxDynamicSharedMemorySize, SMEM_TOTAL);
    attr_set = true;
  }

  // Zero packed buffers (zero padding) and the x2 accumulator.
  hipMemsetAsync(d_ws, 0, ZERO_BYTES, stream);
  hipMemsetAsync(out + X1_N, 0, (size_t)X2_N * sizeof(float), stream);

  prep_kernel<<<dim3((FT2_ELEMS + 255) / 256), 256, 0, stream>>>(ft, fn, fT2);
  feat_kernel<<<dim3(24, 48, 2), 128, 0, stream>>>(x, xprev, fT2, out, prevb);
  pack_kernel<<<dim3((362 * 46 * 32 + 255) / 256), 256, 0, stream>>>(out, filtb);
  corr_kernel<<<dim3(16 * NCHUNKS), 768, SMEM_TOTAL, stream>>>(
      filtb, prevb, out + X1_N);
}

// Round 7
// 276.522 us; speedup vs baseline: 2.7239x; 2.7239x over previous
//
#include <hip/hip_runtime.h>
#include <hip/hip_bf16.h>

// Net_22625887715641: fused conv-feats + channel-normalize + 32x32 normalized
// cross-correlation (23x23 shifts, 362x362 templates).
//
// R17 vs R16 (corr 620us REGRESSION, FETCH 941MB WRITE 1.77GB, MfmaUtil 5%):
//  R16 post-mortem: K=64 scaled MFMA numerics are CORRECT (absmax passed);
//  the regression is register-spill scratch traffic. Explicit 1-deep
//  double-buffering at K=64 put 64 VGPRs of aligned 8-reg operand tuples
//  (Af/Afn 16 + Bf[3]/Bfn[3] 48) on top of acc 48 -> allocator spilled the
//  K-loop operands to scratch every iteration (1.77GB writes = spills).
//  - Minimal live set: per kt load Af once (2x ds_read_b128), reuse across
//    the 3 nt tiles; load ONE Bf (4x ds_read_b64 -> read2_b64 pairs) right
//    before each MFMA. Live: Af 8 + Bf 8 + acc 48 ~= 100 regs < 170 cap.
//  - #pragma unroll 1 on the kt loop caps the scheduler's pipelining
//    window (can't rebuild R16's live set). Latency hiding = 3 waves/SIMD.
//  - Everything else identical to R16: A-ring, B staging, filtb layout
//    [row][kt64][h][kg][o][16B], scaled-MFMA call, epilogue.
//  Pipe model /CU/y: MFMA 3.7k cyc, LDS ~4.6k, vs R15 wall 15.6k.

typedef unsigned short ushort_t;
typedef unsigned int uint_t;
typedef unsigned char uchar_t;
typedef __attribute__((ext_vector_type(4))) float f32x4;
typedef __attribute__((ext_vector_type(16))) float f32x16;
typedef __attribute__((ext_vector_type(4))) uint_t uint4_t;
typedef __attribute__((ext_vector_type(2))) uint_t uint2_t;
typedef __attribute__((ext_vector_type(8))) int int8v;

#define EPSF 2.2204460492503131e-16f
#define X1_N (32*384*384)
#define X2_N (32*32*23*23)

// filtb: fp8 [372 rows][kt64 6][h 2][kg 2][o 32][16B]; row = yf+5
#define FILTB_ROW_B 12288
#define FILTB_BYTES (372*48*32*8)
// prevb: fp8 [32 c][385 rows][432 x]; data rows 0..383 cols 0..383; zeros else
#define PREVB_STRIDE 432
#define PREVB_BYTES (32*385*PREVB_STRIDE)
#define ZERO_BYTES ((size_t)FILTB_BYTES + PREVB_BYTES)
// fT2: fp32 [16 chp][45 rows][12] after prevb
#define FT2_ELEMS (16*45*12)

#define YMAX 367            // y-steps 0..366
#define NCHUNKS 16          // 16 chpairs x 16 chunks = 256 blocks = 1/CU
#define INV_AREA (1.0f/131044.0f)

// One prev y-row image in LDS: [dyb 4][copy 8][432]; copy stride 432
#define SB_COPY_B 432
#define SB_DYB_B  (8*SB_COPY_B)     // 3456
#define SB_ROW_B  (4*SB_DYB_B)      // 13824 B per y-row image
#define SB_BYTES  (2*2*SB_ROW_B)    // [group][buf] = 55296 B

// A-ring: 8 slots x one filtb row
#define SA_BYTES  (8*FILTB_ROW_B)   // 98304 B
#define SMEM_TOTAL (SA_BYTES + SB_BYTES)   // 153600 B

// ---------------------------------------------------------------------------
// fp32 -> fp8 e4m3 (OCP), RNE, input assumed in [0, 448).
// ---------------------------------------------------------------------------
__device__ __forceinline__ uint_t f32_to_e4m3(float f) {
  if (f < 0.015625f)                         // subnormal: m * 2^-9
    return (uint_t)__float2int_rn(f * 512.0f);
  uint_t b = __builtin_bit_cast(uint_t, f);
  int e = (int)(b >> 23) - 127;
  uint_t m = b & 0x7FFFFFu;
  uint_t keep = m >> 20;
  uint_t rest = m & 0xFFFFFu;
  keep += (rest > 0x80000u) || (rest == 0x80000u && (keep & 1u));
  if (keep == 8u) { keep = 0u; e += 1; }
  if (e > 8) return 0x7Eu;                   // saturate 448
  return (uint_t)(((e + 7) << 3) | keep);
}

// ---------------------------------------------------------------------------
// Prep: pack filters to [chp][45][12] (rows 16B-aligned, b-contiguous).
// ---------------------------------------------------------------------------
__global__ void prep_kernel(const float* __restrict__ ft, const float* __restrict__ fn,
                            float* __restrict__ fT2)
{
  const int e = blockIdx.x * 256 + threadIdx.x;
  if (e < FT2_ELEMS) {
    const int chp = e / 540;
    const int rem = e - chp * 540;
    const int row = rem / 12;
    const int j = rem - row * 12;
    float v = 0.f;
    if (j < 11) {
      if (row < 33)      v = ft[chp * 363 + row * 11 + j];        // row = t*11+a
      else if (row < 44) v = fn[chp * 121 + (row - 33) * 11 + j]; // row-33 = a
    }
    fT2[e] = v;
  }
}

// ---------------------------------------------------------------------------
// Stage 1: thread = (ch-pair chp) x (16-px row). Block 128 = 8 rows x 16 chp.
// mode 0: x -> x1 (fp32). mode 1: xprev -> prevb (fp8 e4m3).
// ---------------------------------------------------------------------------
__global__ __launch_bounds__(128, 4) void feat_kernel(
    const float* __restrict__ xcur, const float* __restrict__ xprev,
    const float* __restrict__ fT2,
    float* __restrict__ out_x1, uchar_t* __restrict__ prevb)
{
  __shared__ float sPx[3 * 18 * 28];
  const int tid = threadIdx.x;
  const int chp = tid & 15;
  const int r = tid >> 4;              // 0..7
  const int j0 = blockIdx.x * 16;
  const int i0 = blockIdx.y * 8;
  const int i = i0 + r;
  const int mode = blockIdx.z;
  const float* __restrict__ xin = mode ? xprev : xcur;

  for (int e = tid; e < 3 * 18 * 26; e += 128) {
    const int t = e / 468;
    const int rem = e - t * 468;
    const int ri = rem / 26;
    const int ci = rem - ri * 26;
    sPx[(t * 18 + ri) * 28 + ci] = xin[((size_t)t * 394 + i0 + ri) * 394 + j0 + ci];
  }
  __syncthreads();

  const float* __restrict__ fbase = fT2 + chp * 540;

  float accT[16], accN[16];
#pragma unroll
  for (int p = 0; p < 16; ++p) { accT[p] = 0.f; accN[p] = 0.f; }

#pragma unroll
  for (int t = 0; t < 3; ++t) {
    for (int a = 0; a < 11; ++a) {
      const float* row = &sPx[(t * 18 + r + a) * 28];
      float wv[26];
#pragma unroll
      for (int k = 0; k < 6; ++k) {
        const f32x4 q = *(const f32x4*)(row + 4 * k);
        wv[4 * k + 0] = q[0]; wv[4 * k + 1] = q[1];
        wv[4 * k + 2] = q[2]; wv[4 * k + 3] = q[3];
      }
      wv[24] = row[24]; wv[25] = row[25];

      const float* fr = fbase + (t * 11 + a) * 12;
      const f32x4 fq0 = *(const f32x4*)(fr);
      const f32x4 fq1 = *(const f32x4*)(fr + 4);
      const f32x4 fq2 = *(const f32x4*)(fr + 8);
      float fv[12];
#pragma unroll
      for (int k = 0; k < 4; ++k) { fv[k] = fq0[k]; fv[4+k] = fq1[k]; fv[8+k] = fq2[k]; }
      float fv2[12];
      if (t == 2) {
        const float* fr2 = fbase + (33 + a) * 12;
        const f32x4 g0 = *(const f32x4*)(fr2);
        const f32x4 g1 = *(const f32x4*)(fr2 + 4);
        const f32x4 g2 = *(const f32x4*)(fr2 + 8);
#pragma unroll
        for (int k = 0; k < 4; ++k) { fv2[k] = g0[k]; fv2[4+k] = g1[k]; fv2[8+k] = g2[k]; }
      }

#pragma unroll
      for (int b = 0; b < 11; ++b) {
        const float fT = fv[b];
#pragma unroll
        for (int p = 0; p < 16; ++p) accT[p] = fmaf(wv[b + p], fT, accT[p]);
        if (t == 2) {
          const float fN = fv2[b];
#pragma unroll
          for (int p = 0; p < 16; ++p) accN[p] = fmaf(wv[b + p], fN, accN[p]);
        }
      }
    }
  }

  float o0[16], o1[16];
#pragma unroll
  for (int p = 0; p < 16; ++p) {
    const float vT = fmaxf(accT[p], 0.f) * 0.5f;   // temp: relu(conv)/2
    const float vN = fmaxf(accN[p], 0.f);
    float s = vT + vN;
    s += __shfl_xor(s, 1);  s += __shfl_xor(s, 2);
    s += __shfl_xor(s, 4);  s += __shfl_xor(s, 8);
    const float inv = 1.f / (s + EPSF);
    o0[p] = vT * inv;
    o1[p] = vN * inv;
  }

  if (mode == 0) {
#pragma unroll
    for (int q = 0; q < 4; ++q) {
      f32x4 v0 = {o0[4*q], o0[4*q+1], o0[4*q+2], o0[4*q+3]};
      f32x4 v1 = {o1[4*q], o1[4*q+1], o1[4*q+2], o1[4*q+3]};
      *(f32x4*)(out_x1 + (size_t)chp * 147456 + i * 384 + j0 + 4 * q) = v0;
      *(f32x4*)(out_x1 + (size_t)(chp + 16) * 147456 + i * 384 + j0 + 4 * q) = v1;
    }
  } else {
    uint4_t u0, u1;
#pragma unroll
    for (int q = 0; q < 4; ++q) {
      u0[q] = f32_to_e4m3(o0[4*q]) | (f32_to_e4m3(o0[4*q+1]) << 8) |
              (f32_to_e4m3(o0[4*q+2]) << 16) | (f32_to_e4m3(o0[4*q+3]) << 24);
      u1[q] = f32_to_e4m3(o1[4*q]) | (f32_to_e4m3(o1[4*q+1]) << 8) |
              (f32_to_e4m3(o1[4*q+2]) << 16) | (f32_to_e4m3(o1[4*q+3]) << 24);
    }
    *(uint4_t*)(prevb + ((size_t)chp * 385 + i) * PREVB_STRIDE + j0) = u0;
    *(uint4_t*)(prevb + ((size_t)(chp + 16) * 385 + i) * PREVB_STRIDE + j0) = u1;
  }
}

// ---------------------------------------------------------------------------
// Pack x1 (fp32, cropped) into filtb fp8 MFMA-A layout; coalesced 8B writes.
// Layout per row: [kt64 6][h 2][kg 2][o 32][16B]; element k = xb*8+j:
// kt64 = xb>>3, kg = (xb>>2)&1, h = (xb>>1)&1, byte16 = (xb&1)*8 + j.
// ---------------------------------------------------------------------------
__global__ __launch_bounds__(256) void pack_kernel(
    const float* __restrict__ x1, uchar_t* __restrict__ filtb)
{
  const int e = blockIdx.x * 256 + threadIdx.x;
  if (e >= 362 * 46 * 32) return;
  const int o = e & 31;
  const int q = e >> 5;
  const int xb = q % 46;
  const int rowr = q / 46 + 5;          // 5..366
  const int i = rowr + 6;               // 11..372
  const int j0 = 11 + xb * 8;
  const float* src = x1 + (size_t)o * 147456 + i * 384 + j0;
  uint_t w0 = 0, w1 = 0;
#pragma unroll
  for (int k = 0; k < 4; ++k) {
    w0 |= f32_to_e4m3((j0 + k     <= 372) ? src[k]     : 0.f) << (8 * k);
    w1 |= f32_to_e4m3((j0 + 4 + k <= 372) ? src[4 + k] : 0.f) << (8 * k);
  }
  uint2_t u = {w0, w1};
  const int off = (xb >> 3) * 2048 + ((xb >> 1) & 1) * 1024 +
                  ((xb >> 2) & 1) * 512 + o * 16 + (xb & 1) * 8;
  *(uint2_t*)(filtb + (size_t)rowr * FILTB_ROW_B + off) = u;
}

// ---------------------------------------------------------------------------
// Stage 2: correlation via MX-scaled 32x32x64 fp8 MFMA (unit scales).
//   out[o,c,dy,dx] = sum_{y,x} filt[o][y-dy_a][x] * prev[c][y+6*dy_b][x+dx]
//   M=192=(dy_a 6)x(o 32); N=96: n = dyb*24+dx (dx 0..22, 23=pad);
//   K=(y, x): 6 kt64 steps of 64 per y.
// Block 768 thr = 12 waves = TWO channels (waves 0-5 ch 2p, 6-11 ch 2p+1);
// placement 3,3,3,3 -> balanced pipes. A: 8-slot LDS ring shared by both
// groups, wave w reads ring slot (y+5-w)&7. B: per-group double-buffered
// shifted-copy image (copy s = row byte-shifted by s).
// Operand map (32x32x64 f8f6f4): m/n = lane&31, k = (lane>>5)*32 + j
// (32 contiguous k bytes per lane: A 2x ds_read_b128, B 4x ds_read_b64).
// C/D map: col = lane&31, row = (reg&3)+8*(reg>>2)+4*(lane>>5).
// K-loop: minimal live set (Af + one Bf + acc), #pragma unroll 1 to cap
// the scheduler's pipelining window (R16 spilled with explicit dbuf).
// ---------------------------------------------------------------------------
__global__ __launch_bounds__(768, 3) void corr_kernel(
    const uchar_t* __restrict__ filtb, const uchar_t* __restrict__ prevb,
    float* __restrict__ x2)
{
  extern __shared__ uchar_t smem[];          // [A ring 98304][B 55296]

  const int tid = threadIdx.x;
  const int lane = tid & 63;
  const int wv = tid >> 6;               // 0..11
  const int cg = (wv >= 6) ? 1 : 0;      // channel sub-group
  const int w = wv - 6 * cg;             // 0..5 = dy_a
  const int kg = lane >> 5;              // k-group 0..1
  const int nn = lane & 31;              // n (or o) within tile

  const int chpair = blockIdx.x / NCHUNKS;     // 0..15
  const int chunk = blockIdx.x % NCHUNKS;      // 0..15; %8 == XCD
  const int ch = 2 * chpair + cg;              // 0..31
  const int y0 = (chunk * YMAX) / NCHUNKS;     // balanced 22-23 y-steps
  const int y1 = ((chunk + 1) * YMAX) / NCHUNKS;

  uint_t* const sBg = (uint_t*)(smem + SA_BYTES) + cg * (2 * (SB_ROW_B / 4));

  // Per-lane B window byte offsets within a y-row image (32B contiguous,
  // 8B-aligned): copy s = dx&7 is the row shifted by s bytes.
  int boffB[3];
#pragma unroll
  for (int nt = 0; nt < 3; ++nt) {
    const int n = nt * 32 + nn;          // 0..95
    const int dyb = n / 24;
    const int dxr = n - 24 * dyb;
    const int dx = (dxr < 23) ? dxr : 22;      // pad lane reads valid data
    const int s = dx & 7;
    boffB[nt] = dyb * SB_DYB_B + s * SB_COPY_B + (dx >> 3) * 8 + kg * 32;
  }

  // B staging per group: 104 tasks (dyb = t/26, 16B group g = t%26).
  const int tl = tid - cg * 384;               // 0..383 within group
  const bool st_act = (tl < 104);
  const int sdyb = st_act ? (tl / 26) : 0;
  const int sg = tl - 26 * (st_act ? (tl / 26) : 0);
  const uchar_t* srcbase = prevb + ((size_t)(ch * 385 + 6 * sdyb)) * PREVB_STRIDE;
  const int dstoff = sdyb * (SB_DYB_B / 4) + 4 * sg;   // word offset in buffer

  uint_t st0 = 0, st1 = 0, st2 = 0, st3 = 0, st4 = 0, st5 = 0;

  auto load_st = [&](int yy) {
    const uint_t* sw = (const uint_t*)(srcbase + (size_t)yy * PREVB_STRIDE) + 4 * sg;
    const uint4_t lo = *(const uint4_t*)(sw);
    const uint2_t hi = *(const uint2_t*)(sw + 4);
    st0 = lo.x; st1 = lo.y; st2 = lo.z; st3 = lo.w; st4 = hi.x; st5 = hi.y;
  };

  auto write_shift = [&](int buf) {
    uint_t* dst = sBg + buf * (SB_ROW_B / 4) + dstoff;
    const uint_t wd[6] = {st0, st1, st2, st3, st4, st5};
#pragma unroll
    for (int s = 0; s < 8; ++s) {
      const int off = s >> 2;
      const int b = (s & 3) * 8;
      uint4_t v;
      if (b == 0) {
        v = uint4_t{wd[off], wd[off + 1], wd[off + 2], wd[off + 3]};
      } else {
        v = uint4_t{(wd[off]     >> b) | (wd[off + 1] << (32 - b)),
                    (wd[off + 1] >> b) | (wd[off + 2] << (32 - b)),
                    (wd[off + 2] >> b) | (wd[off + 3] << (32 - b)),
                    (wd[off + 3] >> b) | (wd[off + 4] << (32 - b))};
      }
      *(uint4_t*)(dst + s * (SB_COPY_B / 4)) = v;
    }
  };

  f32x16 acc[3];
#pragma unroll
  for (int nt = 0; nt < 3; ++nt)
#pragma unroll
    for (int r = 0; r < 16; ++r) acc[nt][r] = 0.f;

  // ---- Prologue ----
  // A: stage 6 filt rows y0..y0+5 into ring slots (row&7); 768 thr x 16B.
  {
    uint4_t pv[6];
#pragma unroll
    for (int r6 = 0; r6 < 6; ++r6)
      pv[r6] = *(const uint4_t*)(filtb + (size_t)(y0 + r6) * FILTB_ROW_B + tid * 16);
#pragma unroll
    for (int r6 = 0; r6 < 6; ++r6)
      *(uint4_t*)(smem + ((y0 + r6) & 7) * FILTB_ROW_B + tid * 16) = pv[r6];
  }
  // B: stage y0 into buf 0; preload y0+1 into regs.
  if (st_act) {
    load_st(y0);
    write_shift(0);
    if (y0 + 1 < y1) load_st(y0 + 1);
  }

  __syncthreads();                       // A rows y0..y0+5 + B buf0 staged

  for (int y = y0; y < y1; ++y) {
    const int pb = (y - y0) & 1;         // B buffer being read this iteration

    // A: issue global load of filt row y+6 (used from iteration y+1 on;
    // written to LDS after this K-loop -> a full K-loop of latency cover).
    const bool a_act = (y + 6 <= y1 + 4);
    uint4_t aval;
    if (a_act)
      aval = *(const uint4_t*)(filtb + (size_t)(y + 6) * FILTB_ROW_B + tid * 16);

    // B: stage y+1 into the other buffer; prefetch y+2 into regs.
    if (st_act && y + 1 < y1) write_shift(pb ^ 1);
    if (st_act && y + 2 < y1) load_st(y + 2);

    const char* sBrd = (const char*)sBg + pb * SB_ROW_B;
    const char* aRow = (const char*)smem +
        ((y + 5 - w) & 7) * FILTB_ROW_B + kg * 512 + nn * 16;

    // K-loop: 6 kt64 steps, pure LDS, minimal live registers.
#pragma unroll 1
    for (int kt = 0; kt < 6; ++kt) {
      const char* ap = aRow + (kt << 11);
      const uint4_t a0 = *(const uint4_t*)(ap);          // h=0
      const uint4_t a1 = *(const uint4_t*)(ap + 1024);   // h=1
      const int8v Af = {(int)a0.x, (int)a0.y, (int)a0.z, (int)a0.w,
                        (int)a1.x, (int)a1.y, (int)a1.z, (int)a1.w};
#pragma unroll
      for (int nt = 0; nt < 3; ++nt) {
        const char* bp = sBrd + boffB[nt] + (kt << 6);
        const uint2_t b0 = *(const uint2_t*)(bp);
        const uint2_t b1 = *(const uint2_t*)(bp + 8);
        const uint2_t b2 = *(const uint2_t*)(bp + 16);
        const uint2_t b3 = *(const uint2_t*)(bp + 24);
        const int8v Bf = {(int)b0.x, (int)b0.y, (int)b1.x, (int)b1.y,
                          (int)b2.x, (int)b2.y, (int)b3.x, (int)b3.y};
        acc[nt] = __builtin_amdgcn_mfma_scale_f32_32x32x64_f8f6f4(
            Af, Bf, acc[nt], 0, 0,                // fmtA=FP8, fmtB=FP8
            0, 0x7F7F7F7F, 0, 0x7F7F7F7F);        // unit E8M0 scales
      }
    }

    // A: write staged row into ring slot (y+6)&7 — disjoint from slots
    // {y..y+5}&7 still being read by other waves; safe without a barrier.
    if (a_act)
      *(uint4_t*)(smem + ((y + 6) & 7) * FILTB_ROW_B + tid * 16) = aval;

    __syncthreads();                     // A row y+6 + B buf y+1 visible
  }

  // Epilogue: scale partials, atomically accumulate into x2[o][c][dy][dx].
#pragma unroll
  for (int nt = 0; nt < 3; ++nt) {
    const int n = nt * 32 + nn;
    const int dyb = n / 24;
    const int dxr = n - 24 * dyb;
    if (dxr < 23) {
      const int dy = w + 6 * dyb;
      if (dy <= 22) {
#pragma unroll
        for (int r = 0; r < 16; ++r) {
          const int o = (r & 3) + 8 * (r >> 2) + 4 * kg;   // C/D row
          atomicAdd(&x2[((o * 32 + ch) * 23 + dy) * 23 + dxr],
                    acc[nt][r] * INV_AREA);
        }
      }
    }
  }
}

// ---------------------------------------------------------------------------
extern "C" void kernel_launch(void* const* d_in, const int* in_sizes, int n_in,
                              void* d_out, int out_size, void* d_ws, size_t ws_size,
                              hipStream_t stream)
{
  const float* x     = (const float*)d_in[0];   // [3][394][394]
  const float* xprev = (const float*)d_in[1];
  const float* ft    = (const float*)d_in[2];   // [16][3][11][11]
  const float* fn    = (const float*)d_in[3];   // [16][1][11][11]
  float* out = (float*)d_out;

  uchar_t* filtb = (uchar_t*)d_ws;
  uchar_t* prevb = filtb + FILTB_BYTES;
  float* fT2 = (float*)(prevb + PREVB_BYTES);

  static bool attr_set = false;
  if (!attr_set) {
    (void)hipFuncSetAttribute((const void*)corr_kernel,
        hipFuncAttributeMaxDynamicSharedMemorySize, SMEM_TOTAL);
    attr_set = true;
  }

  // Zero packed buffers (zero padding) and the x2 accumulator.
  hipMemsetAsync(d_ws, 0, ZERO_BYTES, stream);
  hipMemsetAsync(out + X1_N, 0, (size_t)X2_N * sizeof(float), stream);

  prep_kernel<<<dim3((FT2_ELEMS + 255) / 256), 256, 0, stream>>>(ft, fn, fT2);
  feat_kernel<<<dim3(24, 48, 2), 128, 0, stream>>>(x, xprev, fT2, out, prevb);
  pack_kernel<<<dim3((362 * 46 * 32 + 255) / 256), 256, 0, stream>>>(out, filtb);
  corr_kernel<<<dim3(16 * NCHUNKS), 768, SMEM_TOTAL, stream>>>(
      filtb, prevb, out + X1_N);
}